// Round 10
// baseline (114.915 us; speedup 1.0000x reference)
//
#include <hip/hip_runtime.h>

#define N_TOT 8192
#define SEQ_L 512
#define D 128
#define NCHUNK 16
#define CHUNK (N_TOT / NCHUNK)   // 512 cols per j-chunk == one seq block
#define NJT (CHUNK / 64)         // 8 64-col tiles per chunk
#define LOG2E 1.4426950408889634f
#define LN2   0.6931471805599453f

using bf16x8  = __attribute__((ext_vector_type(8))) short;
using f32x4   = __attribute__((ext_vector_type(4))) float;

static __device__ __forceinline__ unsigned short f2bf(float f) {
    unsigned int u = __float_as_uint(f);
    u = (u + 0x7FFFu + ((u >> 16) & 1u)) >> 16;
    return (unsigned short)u;
}
static __device__ __forceinline__ float bf2f(unsigned short h) {
    return __uint_as_float(((unsigned int)h) << 16);
}
static __device__ __forceinline__ float dot8(bf16x8 a, bf16x8 b) {
    float s = 0.f;
    #pragma unroll
    for (int k = 0; k < 8; ++k)
        s = fmaf(bf2f((unsigned short)a[k]), bf2f((unsigned short)b[k]), s);
    return s;
}

// ---------------- one-shot: convert w1/w2 to bf16 ----------------
__global__ __launch_bounds__(256) void convert_w_kernel(
    const float* __restrict__ w1, const float* __restrict__ w2,
    unsigned short* __restrict__ w1b, unsigned short* __restrict__ w2b)
{
    int idx = blockIdx.x * 256 + threadIdx.x;
    const float* src = (idx < 8192) ? w1 : w2;
    unsigned short* dst = (idx < 8192) ? w1b : w2b;
    int off = ((idx < 8192) ? idx : idx - 8192) * 4;
    float4 v = *(const float4*)(src + off);
    ushort4 o;
    o.x = f2bf(v.x); o.y = f2bf(v.y); o.z = f2bf(v.z); o.w = f2bf(v.w);
    *(ushort4*)(dst + off) = o;
}

// ---------------- MFMA MLP (32 rows/block) + fused BN column partials ----------------
__global__ __launch_bounds__(256) void mlp_mfma_kernel(
    const float* __restrict__ x1, const float* __restrict__ x2,
    const unsigned short* __restrict__ w1b, const float* __restrict__ b1,
    const unsigned short* __restrict__ w2b, const float* __restrict__ b2,
    unsigned short* __restrict__ z1, unsigned short* __restrict__ z2,
    float* __restrict__ part_s, float* __restrict__ part_ss)
{
    __shared__ unsigned short hsh[32][264];
    const int t = threadIdx.x;
    const int w = t >> 6;
    const int lane = t & 63;
    const int g = lane >> 4;
    const int c16 = lane & 15;
    const int tensor = blockIdx.x >> 8;
    const int blk = blockIdx.x & 255;
    const int r0 = blk * 32;
    const float* __restrict__ x = tensor ? x2 : x1;
    unsigned short* __restrict__ z = tensor ? z2 : z1;

    // ---- layer 1 ----
    bf16x8 af[2][4];
    #pragma unroll
    for (int rf = 0; rf < 2; ++rf)
        #pragma unroll
        for (int ks = 0; ks < 4; ++ks) {
            const float* xp = x + (size_t)(r0 + rf * 16 + c16) * D + ks * 32 + g * 8;
            float4 u0 = *(const float4*)xp;
            float4 u1 = *(const float4*)(xp + 4);
            bf16x8 a;
            a[0] = f2bf(u0.x); a[1] = f2bf(u0.y); a[2] = f2bf(u0.z); a[3] = f2bf(u0.w);
            a[4] = f2bf(u1.x); a[5] = f2bf(u1.y); a[6] = f2bf(u1.z); a[7] = f2bf(u1.w);
            af[rf][ks] = a;
        }
    f32x4 acc1[2][4] = {};
    #pragma unroll
    for (int ks = 0; ks < 4; ++ks)
        #pragma unroll
        for (int nf = 0; nf < 4; ++nf) {
            int n = w * 64 + nf * 16 + c16;
            bf16x8 b = *(const bf16x8*)(w1b + (size_t)n * D + ks * 32 + g * 8);
            #pragma unroll
            for (int rf = 0; rf < 2; ++rf)
                acc1[rf][nf] = __builtin_amdgcn_mfma_f32_16x16x32_bf16(af[rf][ks], b, acc1[rf][nf], 0, 0, 0);
        }
    #pragma unroll
    for (int nf = 0; nf < 4; ++nf) {
        float bb = b1[w * 64 + nf * 16 + c16];
        #pragma unroll
        for (int rf = 0; rf < 2; ++rf)
            #pragma unroll
            for (int r = 0; r < 4; ++r)
                hsh[rf * 16 + g * 4 + r][w * 64 + nf * 16 + c16] = f2bf(fmaxf(acc1[rf][nf][r] + bb, 0.f));
    }
    __syncthreads();

    // ---- layer 2 ----
    f32x4 acc2[2][2] = {};
    #pragma unroll
    for (int ks = 0; ks < 8; ++ks) {
        bf16x8 a0 = *(const bf16x8*)(&hsh[c16][ks * 32 + g * 8]);
        bf16x8 a1 = *(const bf16x8*)(&hsh[16 + c16][ks * 32 + g * 8]);
        #pragma unroll
        for (int nf = 0; nf < 2; ++nf) {
            int n = w * 32 + nf * 16 + c16;
            bf16x8 b = *(const bf16x8*)(w2b + (size_t)n * 256 + ks * 32 + g * 8);
            acc2[0][nf] = __builtin_amdgcn_mfma_f32_16x16x32_bf16(a0, b, acc2[0][nf], 0, 0, 0);
            acc2[1][nf] = __builtin_amdgcn_mfma_f32_16x16x32_bf16(a1, b, acc2[1][nf], 0, 0, 0);
        }
    }

    // ---- store z + fused BN partials ----
    #pragma unroll
    for (int nf = 0; nf < 2; ++nf) {
        int col = w * 32 + nf * 16 + c16;
        float bb = b2[col];
        float s = 0.f, ss = 0.f;
        #pragma unroll
        for (int rf = 0; rf < 2; ++rf)
            #pragma unroll
            for (int r = 0; r < 4; ++r) {
                float v = acc2[rf][nf][r] + bb;
                z[(size_t)(r0 + rf * 16 + g * 4 + r) * D + col] = f2bf(v);
                s += v; ss += v * v;
            }
        s  += __shfl_xor(s, 16);  s  += __shfl_xor(s, 32);
        ss += __shfl_xor(ss, 16); ss += __shfl_xor(ss, 32);
        if (g == 0) {
            part_s [((size_t)tensor * 256 + blk) * D + col] = s;
            part_ss[((size_t)tensor * 256 + blk) * D + col] = ss;
        }
    }
}

// ---------------- BN reduce ----------------
__global__ __launch_bounds__(256) void bn_reduce_kernel(
    const float* __restrict__ part_s, const float* __restrict__ part_ss,
    const float* __restrict__ gamma,
    float* __restrict__ mu, float* __restrict__ sc)
{
    const int t = threadIdx.x;
    const int tensor = blockIdx.x >> 7;
    const int col = blockIdx.x & 127;
    float s  = part_s [((size_t)tensor * 256 + t) * D + col];
    float ss = part_ss[((size_t)tensor * 256 + t) * D + col];
    #pragma unroll
    for (int m = 32; m; m >>= 1) { s += __shfl_xor(s, m); ss += __shfl_xor(ss, m); }
    __shared__ float rs[4], rss[4];
    if ((t & 63) == 0) { rs[t >> 6] = s; rss[t >> 6] = ss; }
    __syncthreads();
    if (t == 0) {
        float S = rs[0] + rs[1] + rs[2] + rs[3];
        float SS = rss[0] + rss[1] + rss[2] + rss[3];
        float m = S / (float)N_TOT;
        float var = SS / (float)N_TOT - m * m;
        mu[tensor * D + col] = m;
        sc[tensor * D + col] = gamma[col] * rsqrtf(var + 1e-5f);
    }
}

// ---------------- BN apply + L2 normalize; z1 scaled by log2e ----------------
__global__ __launch_bounds__(256) void bn_l2_kernel(
    unsigned short* __restrict__ z1, unsigned short* __restrict__ z2,
    const float* __restrict__ mu, const float* __restrict__ sc,
    const float* __restrict__ beta)
{
    const int t = threadIdx.x;
    const int tensor = blockIdx.x >> 11;
    const int row = (blockIdx.x & 2047) * 4 + (t >> 6);
    const int lane = t & 63;
    unsigned short* __restrict__ yr = (tensor ? z2 : z1) + (size_t)row * D;
    const float* __restrict__ mub = mu + tensor * D;
    const float* __restrict__ scb = sc + tensor * D;

    ushort2 v = ((const ushort2*)yr)[lane];
    float2 m2 = ((const float2*)mub)[lane];
    float2 s2 = ((const float2*)scb)[lane];
    float2 b2 = ((const float2*)beta)[lane];
    float v0 = (bf2f(v.x) - m2.x) * s2.x + b2.x;
    float v1 = (bf2f(v.y) - m2.y) * s2.y + b2.y;
    float ssq = v0 * v0 + v1 * v1;
    #pragma unroll
    for (int m = 32; m; m >>= 1) ssq += __shfl_xor(ssq, m);
    float rn = rsqrtf(ssq);
    if (tensor == 0) rn *= LOG2E;   // pre-scale z1 so loss exp = exp2
    ushort2 o; o.x = f2bf(v0 * rn); o.y = f2bf(v1 * rn);
    ((ushort2*)yr)[lane] = o;
}

// ---------------- diagonal-chunk work (unchanged, verified) ----------------
__global__ __launch_bounds__(256) void diag_kernel(
    const short* __restrict__ z1, const short* __restrict__ z2,
    const int* __restrict__ ids,
    float* __restrict__ posv, float* __restrict__ dden)
{
    const int t = threadIdx.x;
    if (blockIdx.x < 256) {
        const int row = blockIdx.x * 32 + (t >> 3);
        const int le = t & 7;
        const short* ap = z1 + (size_t)row * D + le * 16;
        const short* bp = z2 + (size_t)row * D + le * 16;
        const short* cp = z2 + (size_t)((row + 1) & (N_TOT - 1)) * D + le * 16;
        bf16x8 a0 = *(const bf16x8*)ap, a1 = *(const bf16x8*)(ap + 8);
        float s1 = dot8(a0, *(const bf16x8*)bp) + dot8(a1, *(const bf16x8*)(bp + 8));
        float s2 = dot8(a0, *(const bf16x8*)cp) + dot8(a1, *(const bf16x8*)(cp + 8));
        #pragma unroll
        for (int m = 1; m < 8; m <<= 1) { s1 += __shfl_xor(s1, m); s2 += __shfl_xor(s2, m); }
        if (le == 0) {
            bool two = (row & (SEQ_L - 1)) != (SEQ_L - 1);
            if (two) {
                posv[row] = (s1 + s2) * LN2;
                dden[row] = exp2f(s1) + exp2f(s2);
            } else {
                posv[row] = s1 * LN2;
            }
        }
    } else {
        const int sr = blockIdx.x - 256;
        const int i = sr * SEQ_L + (SEQ_L - 1);
        const int jbase = sr * SEQ_L;
        const int idi_ = ids[i];
        float acc = 0.f;
        #pragma unroll
        for (int c = 0; c < 2; ++c) {
            int j = jbase + t * 2 + c;
            float s = 0.f;
            for (int k = 0; k < 16; ++k) {
                bf16x8 va = *(const bf16x8*)(z1 + (size_t)i * D + k * 8);
                bf16x8 vb = *(const bf16x8*)(z2 + (size_t)j * D + k * 8);
                s += dot8(va, vb);
            }
            bool m = (ids[j] != idi_) | (j == i);
            acc += m ? exp2f(s) : 0.f;
        }
        #pragma unroll
        for (int m = 32; m; m >>= 1) acc += __shfl_xor(acc, m);
        __shared__ float red[4];
        if ((t & 63) == 0) red[t >> 6] = acc;
        __syncthreads();
        if (t == 0) dden[i] = red[0] + red[1] + red[2] + red[3];
    }
}

// ---------------- collision corrections: subtract masked-out exp terms ----------------
// grid 1024 x 256: block -> 8 rows, wave -> 2 rows. Lane l scans j = l+64k.
// For off-seq j with idj==idi (or two && idj==idn): corr += exp2(z1[i].z2[j]).
// Single writer per row -> deterministic. Expected collisions ~2.7K total.
__global__ __launch_bounds__(256) void corr_kernel(
    const short* __restrict__ z1, const short* __restrict__ z2,
    const int* __restrict__ ids, float* __restrict__ corr)
{
    const int t = threadIdx.x;
    const int w = t >> 6;
    const int lane = t & 63;
    const int rbase = blockIdx.x * 8 + w * 2;

    int   idi[2], idn[2], seqi[2];
    bool  two[2];
    float cr[2] = {0.f, 0.f};
    #pragma unroll
    for (int rr = 0; rr < 2; ++rr) {
        int i = rbase + rr;
        idi[rr] = ids[i];
        idn[rr] = ids[(i + 1) & (N_TOT - 1)];
        two[rr] = (i & (SEQ_L - 1)) != (SEQ_L - 1);
        seqi[rr] = i >> 9;
    }

    for (int k = 0; k < N_TOT / 64; ++k) {
        int j = lane + k * 64;
        int idj = ids[j];
        int seqj = j >> 9;
        #pragma unroll
        for (int rr = 0; rr < 2; ++rr) {
            bool hit = (seqj != seqi[rr]) &&
                       ((idj == idi[rr]) || (two[rr] && idj == idn[rr]));
            if (hit) {
                int i = rbase + rr;
                float s = 0.f;
                for (int k2 = 0; k2 < 16; ++k2) {
                    bf16x8 va = *(const bf16x8*)(z1 + (size_t)i * D + k2 * 8);
                    bf16x8 vb = *(const bf16x8*)(z2 + (size_t)j * D + k2 * 8);
                    s += dot8(va, vb);
                }
                cr[rr] += exp2f(s);
            }
        }
    }
    #pragma unroll
    for (int rr = 0; rr < 2; ++rr) {
        float v = cr[rr];
        #pragma unroll
        for (int m = 32; m; m >>= 1) v += __shfl_xor(v, m);
        if (lane == 0) corr[rbase + rr] = v;
    }
}

// ---------------- MFMA S-tile + UNMASKED exp2-sum, off-diagonal chunks ----------------
// grid: 15 chunks x 64 row-blocks = 960. Block = 128 rows x 512 cols; wave w
// owns rows rb+w*32 exclusively. No ids in the hot loop (corrections
// subtracted later). launch_bounds(256,4) forces >=4 waves/SIMD (unified
// VGPR+AGPR cap 128/wave). Per jt: stage-loads -> ds_read+MFMA -> ds_write
// -> barrier -> exp2 epilogue (post-barrier, off the critical section).
__global__ __launch_bounds__(256, 4) void loss_mfma_kernel(
    const short* __restrict__ z1, const short* __restrict__ z2,
    float* __restrict__ den_part)
{
    const int t    = threadIdx.x;
    const int w    = t >> 6;
    const int lane = t & 63;
    const int g    = lane >> 4;
    const int c16  = lane & 15;

    const int c15 = blockIdx.x >> 6;          // 0..14
    const int rbi = blockIdx.x & 63;
    const int rb  = rbi * 128;
    const int seqb = rbi >> 2;
    const int chunk = c15 + (c15 >= seqb);    // skip diagonal chunk
    const int jbase = chunk * CHUNK;

    const int i_wb = rb + w * 32;

    __shared__ __align__(16) unsigned char z2s[2][64 * 256];  // 2 x 16KB

    const int srow = t >> 2;
    const int sq   = t & 3;
    const int wxor = (srow & 7) << 4;         // staging swizzle (per-lane const)
    const int rxor = (c16 & 7) << 4;          // read swizzle (per-lane const)

    bf16x8 af[2][4];
    #pragma unroll
    for (int rf = 0; rf < 2; ++rf)
        #pragma unroll
        for (int ks = 0; ks < 4; ++ks)
            af[rf][ks] = *(const bf16x8*)(z1 + (size_t)(i_wb + rf * 16 + c16) * D + ks * 32 + g * 8);

    // prologue: stage tile 0
    #pragma unroll
    for (int it = 0; it < 4; ++it) {
        bf16x8 v = *(const bf16x8*)(z2 + (size_t)(jbase + srow) * D + sq * 8 + it * 32);
        *(bf16x8*)&z2s[0][srow * 256 + ((sq * 16 + it * 64) ^ wxor)] = v;
    }
    __syncthreads();

    float den_acc[2][4] = {};
    int cbuf = 0;

    #pragma unroll 1
    for (int jt = 0; jt < NJT - 1; ++jt) {
        const int cb = jbase + jt * 64;

        // stage next tile into regs (T14 issue-early)
        bf16x8 stg[4];
        #pragma unroll
        for (int it = 0; it < 4; ++it)
            stg[it] = *(const bf16x8*)(z2 + (size_t)(cb + 64 + srow) * D + sq * 8 + it * 32);

        // compute on current buffer
        f32x4 acc[2][4] = {};
        #pragma unroll
        for (int ks = 0; ks < 4; ++ks)
            #pragma unroll
            for (int nf = 0; nf < 4; ++nf) {
                bf16x8 b = *(const bf16x8*)&z2s[cbuf][(nf * 16 + c16) * 256 + ((ks * 64 + g * 16) ^ rxor)];
                acc[0][nf] = __builtin_amdgcn_mfma_f32_16x16x32_bf16(af[0][ks], b, acc[0][nf], 0, 0, 0);
                acc[1][nf] = __builtin_amdgcn_mfma_f32_16x16x32_bf16(af[1][ks], b, acc[1][nf], 0, 0, 0);
            }

        // write next buffer, then barrier; epilogue runs post-barrier
        #pragma unroll
        for (int it = 0; it < 4; ++it)
            *(bf16x8*)&z2s[cbuf ^ 1][srow * 256 + ((sq * 16 + it * 64) ^ wxor)] = stg[it];
        __syncthreads();

        #pragma unroll
        for (int rf = 0; rf < 2; ++rf)
            #pragma unroll
            for (int nf = 0; nf < 4; ++nf)
                #pragma unroll
                for (int r = 0; r < 4; ++r)
                    den_acc[rf][r] += exp2f(acc[rf][nf][r]);
        cbuf ^= 1;
    }

    // last tile: compute only
    {
        f32x4 acc[2][4] = {};
        #pragma unroll
        for (int ks = 0; ks < 4; ++ks)
            #pragma unroll
            for (int nf = 0; nf < 4; ++nf) {
                bf16x8 b = *(const bf16x8*)&z2s[cbuf][(nf * 16 + c16) * 256 + ((ks * 64 + g * 16) ^ rxor)];
                acc[0][nf] = __builtin_amdgcn_mfma_f32_16x16x32_bf16(af[0][ks], b, acc[0][nf], 0, 0, 0);
                acc[1][nf] = __builtin_amdgcn_mfma_f32_16x16x32_bf16(af[1][ks], b, acc[1][nf], 0, 0, 0);
            }
        #pragma unroll
        for (int rf = 0; rf < 2; ++rf)
            #pragma unroll
            for (int nf = 0; nf < 4; ++nf)
                #pragma unroll
                for (int r = 0; r < 4; ++r)
                    den_acc[rf][r] += exp2f(acc[rf][nf][r]);
    }

    // 16-lane column reduce; single writer per (chunk,row)
    #pragma unroll
    for (int rf = 0; rf < 2; ++rf)
        #pragma unroll
        for (int r = 0; r < 4; ++r) {
            float dsum = den_acc[rf][r];
            #pragma unroll
            for (int m = 8; m; m >>= 1) dsum += __shfl_xor(dsum, m);
            if (c16 == 0)
                den_part[chunk * N_TOT + i_wb + rf * 16 + g * 4 + r] = dsum;
        }
}

// ---------------- combine: den = dden + off-diag - corr; loss scalar ----------------
__global__ __launch_bounds__(1024) void loss_finish_kernel(
    const float* __restrict__ den_part, const float* __restrict__ posv,
    const float* __restrict__ dden, const float* __restrict__ corr,
    float* __restrict__ out)
{
    const int t = threadIdx.x;
    float v = 0.f;
    for (int k = 0; k < N_TOT / 1024; ++k) {
        int row = t + k * 1024;
        int seqb = row >> 9;
        float den = dden[row] - corr[row];
        #pragma unroll
        for (int q = 0; q < NCHUNK; ++q)
            if (q != seqb) den += den_part[q * N_TOT + row];
        bool two = ((row & (SEQ_L - 1)) != (SEQ_L - 1));
        float npos = two ? 2.f : 1.f;
        v += -(posv[row] - logf(den)) / npos;
    }
    #pragma unroll
    for (int m = 32; m; m >>= 1) v += __shfl_xor(v, m);
    __shared__ float red[16];
    if ((t & 63) == 0) red[t >> 6] = v;
    __syncthreads();
    if (t == 0) {
        float tot = 0.f;
        #pragma unroll
        for (int i = 0; i < 16; ++i) tot += red[i];
        out[0] = tot / (float)N_TOT;
    }
}

extern "C" void kernel_launch(void* const* d_in, const int* in_sizes, int n_in,
                              void* d_out, int out_size, void* d_ws, size_t ws_size,
                              hipStream_t stream)
{
    const int*   ids   = (const int*)d_in[0];
    const float* x1    = (const float*)d_in[2];
    const float* x2    = (const float*)d_in[3];
    const float* w1    = (const float*)d_in[4];
    const float* b1    = (const float*)d_in[5];
    const float* w2    = (const float*)d_in[6];
    const float* b2    = (const float*)d_in[7];
    const float* gamma = (const float*)d_in[8];
    const float* beta  = (const float*)d_in[9];

    char* ws = (char*)d_ws;
    unsigned short* z1b = (unsigned short*)ws;                          // 2MB
    unsigned short* z2b = (unsigned short*)(ws + (2u << 20));           // 2MB
    float* part_s  = (float*)(ws + (4u << 20));                         // 256KB
    float* part_ss = part_s + 2 * 256 * D;                              // 256KB
    float* mu      = part_ss + 2 * 256 * D;
    float* sc      = mu + 2 * D;
    float* den_part = sc + 2 * D;                                       // 512KB
    float* posv    = den_part + NCHUNK * N_TOT;                         // 32KB
    float* dden    = posv + N_TOT;                                      // 32KB
    float* corr    = dden + N_TOT;                                      // 32KB
    unsigned short* w1b = (unsigned short*)(corr + N_TOT);              // 64KB
    unsigned short* w2b = w1b + 256 * D;                                // 64KB

    convert_w_kernel<<<64, 256, 0, stream>>>(w1, w2, w1b, w2b);
    mlp_mfma_kernel<<<512, 256, 0, stream>>>(x1, x2, w1b, b1, w2b, b2,
                                             z1b, z2b, part_s, part_ss);
    bn_reduce_kernel<<<256, 256, 0, stream>>>(part_s, part_ss, gamma, mu, sc);
    bn_l2_kernel<<<4096, 256, 0, stream>>>(z1b, z2b, mu, sc, beta);
    diag_kernel<<<272, 256, 0, stream>>>((const short*)z1b, (const short*)z2b,
                                         ids, posv, dden);
    corr_kernel<<<1024, 256, 0, stream>>>((const short*)z1b, (const short*)z2b,
                                          ids, corr);
    loss_mfma_kernel<<<960, 256, 0, stream>>>((const short*)z1b, (const short*)z2b,
                                              den_part);
    loss_finish_kernel<<<1, 1024, 0, stream>>>(den_part, posv, dden, corr,
                                               (float*)d_out);
}